// Round 3
// baseline (240.575 us; speedup 1.0000x reference)
//
#include <hip/hip_runtime.h>

#define NN 4096
#define MM 8192
#define GG 8
#define HH 128
#define NDD 16
#define EE 131072
#define CBLK 64            // cond partial blocks
#define COBJ (MM / CBLK)   // 128 objects per cond block

// ============ K1: zero deg (blocks 0..15) + W1' = Wn@Wc1 (block 16) ============
__global__ __launch_bounds__(256) void k_prep(int* __restrict__ deg,
                                              const float* __restrict__ Wn,
                                              const float* __restrict__ Wc1,
                                              float* __restrict__ W1p) {
    int b = blockIdx.x, t = threadIdx.x;
    if (b < 16) {
        deg[b * 256 + t] = 0;
        return;
    }
    // W1'[a][j] = sum_k Wn[a][k] * Wc1[k][j],  a<16, j<128
    int j = t & 127, a0 = t >> 7;
#pragma unroll
    for (int ai = 0; ai < 8; ai++) {
        int a = a0 + 2 * ai;
        float acc = 0.f;
        for (int k = 0; k < HH; k++) acc += Wn[a * HH + k] * Wc1[k * HH + j];
        W1p[a * HH + j] = acc;
    }
}

// ============ K2: cond partials (blocks 0..63) + degree count (blocks 64..575) ============
__global__ __launch_bounds__(256) void k_cond_deg(
    const float* __restrict__ obj_x, const float* __restrict__ obj_pos,
    const int* __restrict__ nuc, const int* __restrict__ central,
    const int* __restrict__ backbone, const int* __restrict__ obj_batch,
    const float* __restrict__ Wn, const float* __restrict__ bn,
    const int* __restrict__ e_dst, int* __restrict__ deg,
    float* __restrict__ partial, float* __restrict__ pcnt) {
    int b = blockIdx.x, t = threadIdx.x;
    if (b >= CBLK) {
        int e = (b - CBLK) * 256 + t;  // 512*256 == EE exactly
        atomicAdd(&deg[e_dst[e]], 1);
        return;
    }
    __shared__ float ls[GG * HH];
    __shared__ float lc[GG];
    for (int i = t; i < GG * HH; i += 256) ls[i] = 0.f;
    if (t < GG) lc[t] = 0.f;
    __syncthreads();
    int col = t & 127, sub = t >> 7;
    int base = b * COBJ;
    for (int it = 0; it < COBJ / 2; it++) {
        int o = base + it * 2 + sub;
        int nv = nuc[o];
        bool isb = (backbone[o] == 0);
        bool cond = (nv == 0) || ((central[o] != 0) && isb) || ((nv == 2) && isb);
        if (cond) {
            float acc = bn[col];
#pragma unroll
            for (int k = 0; k < 13; k++) acc += obj_x[o * 13 + k] * Wn[k * HH + col];
#pragma unroll
            for (int k = 0; k < 3; k++) acc += obj_pos[o * 3 + k] * Wn[(13 + k) * HH + col];
            int g = obj_batch[o];
            atomicAdd(&ls[g * HH + col], acc);
            if (col == 0) atomicAdd(&lc[g], 1.f);
        }
    }
    __syncthreads();
    for (int i = t; i < GG * HH; i += 256) partial[b * (GG * HH) + i] = ls[i];
    if (t < GG) pcnt[b * GG + t] = lc[t];
}

// ============ K3: block 0 = addh (c1), block 1 = scan (row_ptr/cursor/dinv) ============
__global__ __launch_bounds__(1024) void k_addh_scan(
    const int* __restrict__ timestep, const float* __restrict__ partial,
    const float* __restrict__ pcnt, const float* __restrict__ Wt,
    const float* __restrict__ bt, const float* __restrict__ Wc,
    const float* __restrict__ bc, const float* __restrict__ bn,
    const float* __restrict__ Wc1, float* __restrict__ c1,
    const int* __restrict__ deg, int* __restrict__ row_ptr,
    int* __restrict__ cursor, float* __restrict__ dinv) {
    int t = threadIdx.x;
    if (blockIdx.x == 0) {
        // ---- addh: c1[g] = (bn + time_h[g] + cond_h[g]) @ Wc1 ----
        __shared__ float te[GG * HH];
        __shared__ float pool[GG * HH];
        __shared__ float v2[GG * HH];
        __shared__ float cntsh[GG];
        int g = t >> 7, j = t & 127;
        // reduce cond partials
        float s = 0.f;
        for (int b = 0; b < CBLK; b++) s += partial[b * (GG * HH) + t];
        if (t < GG) {
            float c = 0.f;
            for (int b = 0; b < CBLK; b++) c += pcnt[b * GG + t];
            cntsh[t] = fmaxf(c, 1.f);
        }
        // timestep embedding
        float tv = (float)timestep[g];
        float val;
        if (j < 64) {
            float f = expf(-logf(10000.f) * (float)j / 64.f);
            val = cosf(tv * f);
        } else {
            float f = expf(-logf(10000.f) * (float)(j - 64) / 64.f);
            val = sinf(tv * f);
        }
        te[t] = val;
        __syncthreads();
        pool[t] = s / cntsh[g];
        __syncthreads();
        float acc = bt[j] + bc[j] + bn[j];
        for (int k = 0; k < HH; k++) {
            acc += te[g * HH + k] * Wt[k * HH + j] + pool[g * HH + k] * Wc[k * HH + j];
        }
        v2[t] = acc;
        __syncthreads();
        float cc = 0.f;
        for (int k = 0; k < HH; k++) cc += v2[g * HH + k] * Wc1[k * HH + j];
        c1[t] = cc;
    } else {
        // ---- scan ----
        __shared__ int aux[1024];
        int d[4];
        int s = 0;
#pragma unroll
        for (int i = 0; i < 4; i++) {
            d[i] = deg[t * 4 + i];
            s += d[i];
        }
        aux[t] = s;
        __syncthreads();
        for (int off = 1; off < 1024; off <<= 1) {
            int v = (t >= off) ? aux[t - off] : 0;
            __syncthreads();
            aux[t] += v;
            __syncthreads();
        }
        int run = (t > 0) ? aux[t - 1] : 0;
#pragma unroll
        for (int i = 0; i < 4; i++) {
            int idx = t * 4 + i;
            row_ptr[idx] = run;
            cursor[idx] = run;
            dinv[idx] = rsqrtf((float)(d[i] + 1));  // +1: self loop
            run += d[i];
        }
        if (t == 1023) row_ptr[NN] = run;
    }
}

// ============ K4: scatter (blocks 0..511) + xw1' (blocks 512..1023) ============
// xw1'[i] = (x[i] @ W1' + c1[bm[i]]) * dinv[i]
__global__ __launch_bounds__(256) void k_scatter_xw1(
    const int* __restrict__ e_src, const int* __restrict__ e_dst,
    int* __restrict__ cursor, int* __restrict__ col_idx,
    const float* __restrict__ x, const float* __restrict__ W1p,
    const float* __restrict__ c1, const int* __restrict__ bm,
    const float* __restrict__ dinv, float* __restrict__ xw) {
    int b = blockIdx.x, t = threadIdx.x;
    __shared__ float xt[8 * NDD];
    if (b < 512) {
        int e = b * 256 + t;
        int pos = atomicAdd(&cursor[e_dst[e]], 1);
        col_idx[pos] = e_src[e];
        return;
    }
    int r0 = (b - 512) * 8;
    if (t < 128) xt[t] = x[r0 * NDD + t];
    __syncthreads();
    int col = t & 127, rh = t >> 7;
#pragma unroll
    for (int i = 0; i < 4; i++) {
        int r = rh * 4 + i;
        int row = r0 + r;
        float acc = c1[bm[row] * HH + col];
#pragma unroll
        for (int k = 0; k < NDD; k++) acc += xt[r * NDD + k] * W1p[k * HH + col];
        xw[row * HH + col] = acc * dinv[row];
    }
}

// ============ K5: agg1  h1 = relu(dd*(sum_{s in N} xw'[s] + xw'[dst]) + b1) ============
__global__ __launch_bounds__(128) void k_agg1(const float* __restrict__ xw,
                                              const int* __restrict__ row_ptr,
                                              const int* __restrict__ col_idx,
                                              const float* __restrict__ dinv,
                                              const float* __restrict__ bias,
                                              float* __restrict__ out) {
    int dst = blockIdx.x, t = threadIdx.x;
    float dd = dinv[dst];
    float acc = xw[dst * HH + t];  // self loop (pre-scaled)
    int beg = row_ptr[dst], end = row_ptr[dst + 1];
    int e = beg;
    for (; e + 3 < end; e += 4) {
        int s0 = col_idx[e], s1 = col_idx[e + 1], s2 = col_idx[e + 2], s3 = col_idx[e + 3];
        float v0 = xw[s0 * HH + t], v1 = xw[s1 * HH + t];
        float v2 = xw[s2 * HH + t], v3 = xw[s3 * HH + t];
        acc += (v0 + v1) + (v2 + v3);
    }
    for (; e < end; e++) acc += xw[col_idx[e] * HH + t];
    out[dst * HH + t] = fmaxf(dd * acc + bias[t], 0.f);
}

// ============ K6: gemm2  xw2'[i] = (h1[i] @ Wc2) * dinv[i] ============
__global__ __launch_bounds__(256) void k_gemm2(const float* __restrict__ A,
                                               const float* __restrict__ W,
                                               const float* __restrict__ dinv,
                                               float* __restrict__ out) {
    __shared__ float At[8 * HH];
    int r0 = blockIdx.x * 8, t = threadIdx.x;
    ((float4*)At)[t] = ((const float4*)(A + r0 * HH))[t];  // 8x128 tile, coalesced
    __syncthreads();
    int col = t & 127, rh = t >> 7;
    float acc[4] = {0.f, 0.f, 0.f, 0.f};
#pragma unroll 4
    for (int k = 0; k < HH; k++) {
        float w = W[k * HH + col];
#pragma unroll
        for (int i = 0; i < 4; i++) acc[i] += At[(rh * 4 + i) * HH + k] * w;
    }
#pragma unroll
    for (int i = 0; i < 4; i++) {
        int row = r0 + rh * 4 + i;
        out[row * HH + col] = acc[i] * dinv[row];
    }
}

// ============ K7: agg2 + pred + sl/sr (h2 never leaves the block) ============
__global__ __launch_bounds__(128) void k_agg2_head(
    const float* __restrict__ xw, const int* __restrict__ row_ptr,
    const int* __restrict__ col_idx, const float* __restrict__ dinv,
    const float* __restrict__ bias, const float* __restrict__ Wo,
    const float* __restrict__ bo, const float* __restrict__ we,
    float* __restrict__ out_pred, float* __restrict__ sl, float* __restrict__ sr) {
    int dst = blockIdx.x, t = threadIdx.x;
    float dd = dinv[dst];
    float acc = xw[dst * HH + t];
    int beg = row_ptr[dst], end = row_ptr[dst + 1];
    int e = beg;
    for (; e + 3 < end; e += 4) {
        int s0 = col_idx[e], s1 = col_idx[e + 1], s2 = col_idx[e + 2], s3 = col_idx[e + 3];
        float v0 = xw[s0 * HH + t], v1 = xw[s1 * HH + t];
        float v2 = xw[s2 * HH + t], v3 = xw[s3 * HH + t];
        acc += (v0 + v1) + (v2 + v3);
    }
    for (; e < end; e++) acc += xw[col_idx[e] * HH + t];
    float h = fmaxf(dd * acc + bias[t], 0.f);

    __shared__ float hr[HH];
    hr[t] = h;
    __syncthreads();
    if (t < 64) {
        // pred: 16 outputs, 4 lanes each (lane = c + 16*p, partial over k in [32p,32p+32))
        int c = t & 15, p = t >> 4;
        float a = 0.f;
        for (int k = p * 32; k < p * 32 + 32; k++) a += hr[k] * Wo[k * NDD + c];
        a += __shfl_xor(a, 16);
        a += __shfl_xor(a, 32);
        if (p == 0) out_pred[dst * NDD + c] = a + bo[c];
    } else {
        // sl/sr: wave-1 shuffle reduction
        int l = t - 64;
        float h0 = hr[l], h1 = hr[64 + l];
        float pl = h0 * we[l] + h1 * we[64 + l];
        float pr = h0 * we[HH + l] + h1 * we[HH + 64 + l];
        for (int off = 32; off; off >>= 1) {
            pl += __shfl_down(pl, off);
            pr += __shfl_down(pr, off);
        }
        if (l == 0) {
            sl[dst] = pl;
            sr[dst] = pr;
        }
    }
}

// ============ K8: edge logits, float4 stores, rows b and NN-2-b per block ============
__global__ __launch_bounds__(256) void k_edges(const float* __restrict__ sl,
                                               const float* __restrict__ sr,
                                               const float* __restrict__ be_p,
                                               float* __restrict__ out) {
    int b = blockIdx.x, t = threadIdx.x;
    float be = be_p[0];
#pragma unroll
    for (int half = 0; half < 2; half++) {
        int r = half == 0 ? b : (NN - 2 - b);
        int off = r * (2 * NN - r - 1) / 2;  // < 2^23, fits int
        int len = NN - 1 - r;
        float s = sl[r] + be;
        const float* sp = sr + r + 1;
        float* op = out + off;
        int hd = (4 - (off & 3)) & 3;
        if (hd > len) hd = len;
        if (t < hd) op[t] = s + sp[t];
        int body = (len - hd) >> 2;
        float* opb = op + hd;
        const float* spb = sp + hd;
        for (int i = t; i < body; i += 256) {
            int base = 4 * i;
            float4 v;
            v.x = s + spb[base];
            v.y = s + spb[base + 1];
            v.z = s + spb[base + 2];
            v.w = s + spb[base + 3];
            *(float4*)(opb + base) = v;
        }
        int tail = hd + body * 4;
        int rem = len - tail;
        if (t < rem) op[tail + t] = s + sp[tail + t];
    }
}

extern "C" void kernel_launch(void* const* d_in, const int* in_sizes, int n_in,
                              void* d_out, int out_size, void* d_ws, size_t ws_size,
                              hipStream_t stream) {
    const float* x = (const float*)d_in[0];
    const int* edge = (const int*)d_in[1];
    const int* timestep = (const int*)d_in[2];
    const int* batch_map = (const int*)d_in[3];
    const int* nuc = (const int*)d_in[4];
    const int* central = (const int*)d_in[5];
    const int* backbone = (const int*)d_in[6];
    const float* obj_x = (const float*)d_in[7];
    const float* obj_pos = (const float*)d_in[8];
    const int* obj_batch = (const int*)d_in[9];
    const float* W_node = (const float*)d_in[10];
    const float* b_node = (const float*)d_in[11];
    const float* W_cond = (const float*)d_in[12];
    const float* b_cond = (const float*)d_in[13];
    const float* W_time = (const float*)d_in[14];
    const float* b_time = (const float*)d_in[15];
    const float* W_conv1 = (const float*)d_in[16];
    const float* b_conv1 = (const float*)d_in[17];
    const float* W_conv2 = (const float*)d_in[18];
    const float* b_conv2 = (const float*)d_in[19];
    const float* W_out = (const float*)d_in[20];
    const float* b_out = (const float*)d_in[21];
    const float* w_edge = (const float*)d_in[22];
    const float* b_edge = (const float*)d_in[23];

    const int* e_src = edge;
    const int* e_dst = edge + EE;

    // workspace
    float* ws = (float*)d_ws;
    float* bufA = ws;                     // N*H (xw1', then xw2')
    float* bufB = bufA + NN * HH;         // N*H (h1)
    float* W1p = bufB + NN * HH;          // 16*H
    float* c1 = W1p + NDD * HH;           // G*H
    float* partial = c1 + GG * HH;        // CBLK*G*H
    float* pcnt = partial + CBLK * GG * HH;  // CBLK*G
    float* dinv = pcnt + CBLK * GG;       // N
    float* sl = dinv + NN;                // N
    float* sr = sl + NN;                  // N
    int* deg = (int*)(sr + NN);           // N
    int* row_ptr = deg + NN;              // N+1
    int* cursor = row_ptr + NN + 1;       // N
    int* col_idx = cursor + NN;           // E

    float* out_pred = (float*)d_out;
    float* out_edges = out_pred + NN * NDD;

    // K1: zero deg + W1' = Wn@Wc1
    k_prep<<<17, 256, 0, stream>>>(deg, W_node, W_conv1, W1p);
    // K2: cond partials + degree
    k_cond_deg<<<CBLK + 512, 256, 0, stream>>>(obj_x, obj_pos, nuc, central,
                                               backbone, obj_batch, W_node, b_node,
                                               e_dst, deg, partial, pcnt);
    // K3: addh (c1) + scan
    k_addh_scan<<<2, 1024, 0, stream>>>(timestep, partial, pcnt, W_time, b_time,
                                        W_cond, b_cond, b_node, W_conv1, c1, deg,
                                        row_ptr, cursor, dinv);
    // K4: CSR scatter + xw1'
    k_scatter_xw1<<<1024, 256, 0, stream>>>(e_src, e_dst, cursor, col_idx, x, W1p,
                                            c1, batch_map, dinv, bufA);
    // K5: agg1 -> h1
    k_agg1<<<NN, 128, 0, stream>>>(bufA, row_ptr, col_idx, dinv, b_conv1, bufB);
    // K6: gemm2 -> xw2'
    k_gemm2<<<NN / 8, 256, 0, stream>>>(bufB, W_conv2, dinv, bufA);
    // K7: agg2 + pred + sl/sr
    k_agg2_head<<<NN, 128, 0, stream>>>(bufA, row_ptr, col_idx, dinv, b_conv2,
                                        W_out, b_out, w_edge, out_pred, sl, sr);
    // K8: edge logits
    k_edges<<<NN / 2, 256, 0, stream>>>(sl, sr, b_edge, out_edges);
}

// Round 5
// 216.258 us; speedup vs baseline: 1.1124x; 1.1124x over previous
//
#include <hip/hip_runtime.h>

#define NN 4096
#define MM 8192
#define GG 8
#define HH 128
#define NDD 16
#define EE 131072
#define CBLK 64            // cond partial blocks
#define COBJ (MM / CBLK)   // 128 objects per cond block

typedef float nt_f4 __attribute__((ext_vector_type(4)));

// ============ K_A: cond input-space partials (0..63) + deg count int4 (64..191) + W1p (192) ============
__global__ __launch_bounds__(256) void k_front(
    const float* __restrict__ obj_x, const float* __restrict__ obj_pos,
    const int* __restrict__ nuc, const int* __restrict__ central,
    const int* __restrict__ backbone, const int* __restrict__ obj_batch,
    const int* __restrict__ e_dst, int* __restrict__ deg,
    float* __restrict__ partial, float* __restrict__ pcnt,
    const float* __restrict__ Wn, const float* __restrict__ Wc1,
    float* __restrict__ W1p) {
    int b = blockIdx.x, t = threadIdx.x;
    if (b >= CBLK && b < CBLK + 128) {
        // degree count, 4 edges/thread via int4
        int4 d4 = ((const int4*)e_dst)[(b - CBLK) * 256 + t];
        atomicAdd(&deg[d4.x], 1);
        atomicAdd(&deg[d4.y], 1);
        atomicAdd(&deg[d4.z], 1);
        atomicAdd(&deg[d4.w], 1);
        return;
    }
    if (b >= CBLK) {
        // W1'[a][j] = sum_k Wn[a][k] * Wc1[k][j]
        int j = t & 127, a0 = t >> 7;
#pragma unroll
        for (int ai = 0; ai < 8; ai++) {
            int a = a0 + 2 * ai;
            float acc = 0.f;
            for (int k = 0; k < HH; k++) acc += Wn[a * HH + k] * Wc1[k * HH + j];
            W1p[a * HH + j] = acc;
        }
        return;
    }
    // cond: pool 16-dim inputs. thread: d = t&15, oi = t>>4 (16 objs parallel, 8 passes)
    __shared__ float ls[GG * NDD];
    __shared__ float lc[GG];
    if (t < GG * NDD) ls[t] = 0.f;
    if (t < GG) lc[t] = 0.f;
    __syncthreads();
    int d = t & 15, oi = t >> 4;
    int base = b * COBJ;
#pragma unroll
    for (int pass = 0; pass < COBJ / 16; pass++) {
        int o = base + pass * 16 + oi;
        int nv = nuc[o];
        bool isb = (backbone[o] == 0);
        bool cond = (nv == 0) || ((central[o] != 0) && isb) || ((nv == 2) && isb);
        if (cond) {
            float v = (d < 13) ? obj_x[o * 13 + d] : obj_pos[o * 3 + (d - 13)];
            int g = obj_batch[o];
            atomicAdd(&ls[g * NDD + d], v);
            if (d == 0) atomicAdd(&lc[g], 1.f);
        }
    }
    __syncthreads();
    if (t < GG * NDD) partial[b * (GG * NDD) + t] = ls[t];
    if (t < GG) pcnt[b * GG + t] = lc[t];
}

// ============ K_B: block 0 = c1 (addh folded through Wc1), block 1 = scan ============
__global__ __launch_bounds__(1024) void k_addh_scan(
    const int* __restrict__ timestep, const float* __restrict__ partial,
    const float* __restrict__ pcnt, const float* __restrict__ Wn,
    const float* __restrict__ bn, const float* __restrict__ Wt,
    const float* __restrict__ bt, const float* __restrict__ Wc,
    const float* __restrict__ bc, const float* __restrict__ Wc1,
    float* __restrict__ c1, const int* __restrict__ deg,
    int* __restrict__ row_ptr, int* __restrict__ cursor,
    float* __restrict__ dinv) {
    int t = threadIdx.x;
    if (blockIdx.x == 0) {
        __shared__ float s16[GG * NDD];
        __shared__ float cinv[GG];
        __shared__ float te[GG * HH];
        __shared__ float pool[GG * HH];
        __shared__ float v2[GG * HH];
        int g = t >> 7, j = t & 127;
        if (t < GG * NDD) {
            float s = 0.f;
            for (int b = 0; b < CBLK; b++) s += partial[b * (GG * NDD) + t];
            s16[t] = s;
        }
        if (t < GG) {
            float c = 0.f;
            for (int b = 0; b < CBLK; b++) c += pcnt[b * GG + t];
            cinv[t] = 1.f / fmaxf(c, 1.f);
        }
        // timestep embedding
        float tv = (float)timestep[g];
        float val;
        if (j < 64) {
            float f = expf(-logf(10000.f) * (float)j / 64.f);
            val = cosf(tv * f);
        } else {
            float f = expf(-logf(10000.f) * (float)(j - 64) / 64.f);
            val = sinf(tv * f);
        }
        te[t] = val;
        __syncthreads();
        // pooled embedding: mean(cond_x)@Wn + bn
        float p = bn[j];
#pragma unroll
        for (int d = 0; d < NDD; d++) p += s16[g * NDD + d] * cinv[g] * Wn[d * HH + j];
        pool[t] = p;
        __syncthreads();
        float acc = bt[j] + bc[j] + bn[j];
        for (int k = 0; k < HH; k++) {
            acc += te[g * HH + k] * Wt[k * HH + j] + pool[g * HH + k] * Wc[k * HH + j];
        }
        v2[t] = acc;
        __syncthreads();
        float cc = 0.f;
        for (int k = 0; k < HH; k++) cc += v2[g * HH + k] * Wc1[k * HH + j];
        c1[t] = cc;
    } else {
        __shared__ int aux[1024];
        int d[4];
        int s = 0;
#pragma unroll
        for (int i = 0; i < 4; i++) {
            d[i] = deg[t * 4 + i];
            s += d[i];
        }
        aux[t] = s;
        __syncthreads();
        for (int off = 1; off < 1024; off <<= 1) {
            int v = (t >= off) ? aux[t - off] : 0;
            __syncthreads();
            aux[t] += v;
            __syncthreads();
        }
        int run = (t > 0) ? aux[t - 1] : 0;
#pragma unroll
        for (int i = 0; i < 4; i++) {
            int idx = t * 4 + i;
            row_ptr[idx] = run;
            cursor[idx] = run;
            dinv[idx] = rsqrtf((float)(d[i] + 1));  // +1: self loop
            run += d[i];
        }
        if (t == 1023) row_ptr[NN] = run;
    }
}

// ============ K_C: scatter int4 (0..127) + xw1' (128..639) ============
// xw1'[i] = (x[i] @ W1' + c1[bm[i]]) * dinv[i]
__global__ __launch_bounds__(256) void k_scatter_xw1(
    const int* __restrict__ e_src, const int* __restrict__ e_dst,
    int* __restrict__ cursor, int* __restrict__ col_idx,
    const float* __restrict__ x, const float* __restrict__ W1p,
    const float* __restrict__ c1, const int* __restrict__ bm,
    const float* __restrict__ dinv, float* __restrict__ xw) {
    int b = blockIdx.x, t = threadIdx.x;
    __shared__ float xt[8 * NDD];
    if (b < 128) {
        int i4 = b * 256 + t;
        int4 d4 = ((const int4*)e_dst)[i4];
        int4 s4 = ((const int4*)e_src)[i4];
        int p;
        p = atomicAdd(&cursor[d4.x], 1); col_idx[p] = s4.x;
        p = atomicAdd(&cursor[d4.y], 1); col_idx[p] = s4.y;
        p = atomicAdd(&cursor[d4.z], 1); col_idx[p] = s4.z;
        p = atomicAdd(&cursor[d4.w], 1); col_idx[p] = s4.w;
        return;
    }
    int r0 = (b - 128) * 8;
    if (t < 128) xt[t] = x[r0 * NDD + t];
    __syncthreads();
    int col = t & 127, rh = t >> 7;
#pragma unroll
    for (int i = 0; i < 4; i++) {
        int r = rh * 4 + i;
        int row = r0 + r;
        float acc = c1[bm[row] * HH + col];
#pragma unroll
        for (int k = 0; k < NDD; k++) acc += xt[r * NDD + k] * W1p[k * HH + col];
        xw[row * HH + col] = acc * dinv[row];
    }
}

// ============ K_D: conv1 aggregate + fused gemm2. One 64-lane wave per dst row. ============
// h1 = relu(dd*(self+sum) + b1)   (kept in LDS only)
// xw2'[dst] = (h1 @ Wc2) * dd
__global__ __launch_bounds__(256) void k_conv1(
    const float* __restrict__ xw, const int* __restrict__ row_ptr,
    const int* __restrict__ col_idx, const float* __restrict__ dinv,
    const float* __restrict__ b1, const float* __restrict__ Wc2,
    float* __restrict__ xw2) {
    int w = threadIdx.x >> 6, l = threadIdx.x & 63;
    int dst = blockIdx.x * 4 + w;
    const float2* xwp = (const float2*)xw;
    float2 acc = xwp[dst * 64 + l];  // self loop, pre-scaled
    int beg = row_ptr[dst], end = row_ptr[dst + 1];
    int e = beg;
    for (; e + 3 < end; e += 4) {
        int s0 = col_idx[e], s1 = col_idx[e + 1], s2 = col_idx[e + 2], s3 = col_idx[e + 3];
        float2 v0 = xwp[s0 * 64 + l], v1 = xwp[s1 * 64 + l];
        float2 v2 = xwp[s2 * 64 + l], v3 = xwp[s3 * 64 + l];
        acc.x += (v0.x + v1.x) + (v2.x + v3.x);
        acc.y += (v0.y + v1.y) + (v2.y + v3.y);
    }
    for (; e < end; e++) {
        float2 v = xwp[col_idx[e] * 64 + l];
        acc.x += v.x;
        acc.y += v.y;
    }
    float dd = dinv[dst];
    float2 h;
    h.x = fmaxf(dd * acc.x + b1[2 * l], 0.f);
    h.y = fmaxf(dd * acc.y + b1[2 * l + 1], 0.f);
    __shared__ float hr[4][HH];
    *(float2*)&hr[w][2 * l] = h;
    __syncthreads();
    // gemm: out cols (2l, 2l+1)
    float2 o = {0.f, 0.f};
#pragma unroll 4
    for (int k = 0; k < HH; k++) {
        float hk = hr[w][k];
        float2 wv = *(const float2*)&Wc2[k * HH + 2 * l];
        o.x += hk * wv.x;
        o.y += hk * wv.y;
    }
    o.x *= dd;
    o.y *= dd;
    ((float2*)xw2)[dst * 64 + l] = o;
}

// ============ K_F: conv2 aggregate + pred + sl/sr. One wave per dst row. ============
__global__ __launch_bounds__(256) void k_conv2_head(
    const float* __restrict__ xw, const int* __restrict__ row_ptr,
    const int* __restrict__ col_idx, const float* __restrict__ dinv,
    const float* __restrict__ b2, const float* __restrict__ Wo,
    const float* __restrict__ bo, const float* __restrict__ we,
    float* __restrict__ out_pred, float* __restrict__ sl, float* __restrict__ sr) {
    int w = threadIdx.x >> 6, l = threadIdx.x & 63;
    int dst = blockIdx.x * 4 + w;
    const float2* xwp = (const float2*)xw;
    float2 acc = xwp[dst * 64 + l];
    int beg = row_ptr[dst], end = row_ptr[dst + 1];
    int e = beg;
    for (; e + 3 < end; e += 4) {
        int s0 = col_idx[e], s1 = col_idx[e + 1], s2 = col_idx[e + 2], s3 = col_idx[e + 3];
        float2 v0 = xwp[s0 * 64 + l], v1 = xwp[s1 * 64 + l];
        float2 v2 = xwp[s2 * 64 + l], v3 = xwp[s3 * 64 + l];
        acc.x += (v0.x + v1.x) + (v2.x + v3.x);
        acc.y += (v0.y + v1.y) + (v2.y + v3.y);
    }
    for (; e < end; e++) {
        float2 v = xwp[col_idx[e] * 64 + l];
        acc.x += v.x;
        acc.y += v.y;
    }
    float dd = dinv[dst];
    float2 h;
    h.x = fmaxf(dd * acc.x + b2[2 * l], 0.f);
    h.y = fmaxf(dd * acc.y + b2[2 * l + 1], 0.f);
    __shared__ float hr[4][HH];
    *(float2*)&hr[w][2 * l] = h;
    __syncthreads();
    // pred: c = l&15, partial p = l>>4 over k in [32p, 32p+32)
    {
        int c = l & 15, p = l >> 4;
        float a = 0.f;
#pragma unroll 4
        for (int k = p * 32; k < p * 32 + 32; k++) a += hr[w][k] * Wo[k * NDD + c];
        a += __shfl_xor(a, 16);
        a += __shfl_xor(a, 32);
        if (p == 0) out_pred[dst * NDD + c] = a + bo[c];
    }
    // sl/sr
    {
        float h0 = hr[w][l], h1v = hr[w][64 + l];
        float pl = h0 * we[l] + h1v * we[64 + l];
        float pr = h0 * we[HH + l] + h1v * we[HH + 64 + l];
        for (int off = 32; off; off >>= 1) {
            pl += __shfl_down(pl, off);
            pr += __shfl_down(pr, off);
        }
        if (l == 0) {
            sl[dst] = pl;
            sr[dst] = pr;
        }
    }
}

// ============ K_G: edge logits, nontemporal ext-vector stores, rows b and NN-2-b ============
__global__ __launch_bounds__(256) void k_edges(const float* __restrict__ sl,
                                               const float* __restrict__ sr,
                                               const float* __restrict__ be_p,
                                               float* __restrict__ out) {
    int b = blockIdx.x, t = threadIdx.x;
    float be = be_p[0];
#pragma unroll
    for (int half = 0; half < 2; half++) {
        int r = half == 0 ? b : (NN - 2 - b);
        int off = r * (2 * NN - r - 1) / 2;  // < 2^23, fits int
        int len = NN - 1 - r;
        float s = sl[r] + be;
        const float* sp = sr + r + 1;
        float* op = out + off;
        int hd = (4 - (off & 3)) & 3;
        if (hd > len) hd = len;
        if (t < hd) __builtin_nontemporal_store(s + sp[t], op + t);
        int body = (len - hd) >> 2;
        float* opb = op + hd;
        const float* spb = sp + hd;
        for (int i = t; i < body; i += 256) {
            int base = 4 * i;
            nt_f4 v;
            v.x = s + spb[base];
            v.y = s + spb[base + 1];
            v.z = s + spb[base + 2];
            v.w = s + spb[base + 3];
            __builtin_nontemporal_store(v, (nt_f4*)(opb + base));
        }
        int tail = hd + body * 4;
        int rem = len - tail;
        if (t < rem) __builtin_nontemporal_store(s + sp[tail + t], op + tail + t);
    }
}

extern "C" void kernel_launch(void* const* d_in, const int* in_sizes, int n_in,
                              void* d_out, int out_size, void* d_ws, size_t ws_size,
                              hipStream_t stream) {
    const float* x = (const float*)d_in[0];
    const int* edge = (const int*)d_in[1];
    const int* timestep = (const int*)d_in[2];
    const int* batch_map = (const int*)d_in[3];
    const int* nuc = (const int*)d_in[4];
    const int* central = (const int*)d_in[5];
    const int* backbone = (const int*)d_in[6];
    const float* obj_x = (const float*)d_in[7];
    const float* obj_pos = (const float*)d_in[8];
    const int* obj_batch = (const int*)d_in[9];
    const float* W_node = (const float*)d_in[10];
    const float* b_node = (const float*)d_in[11];
    const float* W_cond = (const float*)d_in[12];
    const float* b_cond = (const float*)d_in[13];
    const float* W_time = (const float*)d_in[14];
    const float* b_time = (const float*)d_in[15];
    const float* W_conv1 = (const float*)d_in[16];
    const float* b_conv1 = (const float*)d_in[17];
    const float* W_conv2 = (const float*)d_in[18];
    const float* b_conv2 = (const float*)d_in[19];
    const float* W_out = (const float*)d_in[20];
    const float* b_out = (const float*)d_in[21];
    const float* w_edge = (const float*)d_in[22];
    const float* b_edge = (const float*)d_in[23];

    const int* e_src = edge;
    const int* e_dst = edge + EE;

    // workspace
    float* ws = (float*)d_ws;
    float* bufA = ws;                        // N*H (xw1')
    float* bufB = bufA + NN * HH;            // N*H (xw2')
    float* W1p = bufB + NN * HH;             // 16*H
    float* c1 = W1p + NDD * HH;              // G*H
    float* partial = c1 + GG * HH;           // CBLK*G*16
    float* pcnt = partial + CBLK * GG * NDD; // CBLK*G
    float* dinv = pcnt + CBLK * GG;          // N
    float* sl = dinv + NN;                   // N
    float* sr = sl + NN;                     // N
    int* deg = (int*)(sr + NN);              // N
    int* row_ptr = deg + NN;                 // N+1
    int* cursor = row_ptr + NN + 1;          // N
    int* col_idx = cursor + NN;              // E

    float* out_pred = (float*)d_out;
    float* out_edges = out_pred + NN * NDD;

    // zero deg
    (void)hipMemsetAsync(deg, 0, NN * sizeof(int), stream);
    // K_A: cond16 partials + deg count + W1p
    k_front<<<CBLK + 128 + 1, 256, 0, stream>>>(obj_x, obj_pos, nuc, central,
                                                backbone, obj_batch, e_dst, deg,
                                                partial, pcnt, W_node, W_conv1, W1p);
    // K_B: c1 + scan
    k_addh_scan<<<2, 1024, 0, stream>>>(timestep, partial, pcnt, W_node, b_node,
                                        W_time, b_time, W_cond, b_cond, W_conv1,
                                        c1, deg, row_ptr, cursor, dinv);
    // K_C: scatter + xw1'
    k_scatter_xw1<<<128 + 512, 256, 0, stream>>>(e_src, e_dst, cursor, col_idx, x,
                                                 W1p, c1, batch_map, dinv, bufA);
    // K_D: conv1 agg + gemm2 -> xw2'
    k_conv1<<<NN / 4, 256, 0, stream>>>(bufA, row_ptr, col_idx, dinv, b_conv1,
                                        W_conv2, bufB);
    // K_F: conv2 agg + pred + sl/sr
    k_conv2_head<<<NN / 4, 256, 0, stream>>>(bufB, row_ptr, col_idx, dinv, b_conv2,
                                             W_out, b_out, w_edge, out_pred, sl, sr);
    // K_G: edge logits
    k_edges<<<NN / 2, 256, 0, stream>>>(sl, sr, b_edge, out_edges);
}